// Round 6
// baseline (619.115 us; speedup 1.0000x reference)
//
#include <hip/hip_runtime.h>
#include <hip/hip_bf16.h>

typedef __hip_bfloat16 bf16;
typedef short bf16x8 __attribute__((ext_vector_type(8)));   // 8 bf16 = 16B (4 VGPRs)
typedef float f32x4 __attribute__((ext_vector_type(4)));

#define ND     40962
#define NUP    163842
#define NBATCH 2
#define NTC    2561            // ceil(NUP/64)  conv M-tiles (64 nodes/block)
#define NT64   2561
#define BN_EPS 1e-5
#define SLOPE  0.2f

// ---- ws layout (bytes), all 256-aligned ----
#define OFF_W1P   0ull                      // 64*896*2  = 114688
#define OFF_W2P   114688ull                 // 64*448*2  = 57344
#define OFF_STATS 172032ull                 // sc[64]+sh[64] fp32 = 512
#define OFF_H     173056ull                 // h bf16: 2*40962*64*2 = 10486272 ; partials alias
#define OFF_P2    (OFF_H + 2622464ull)      // p2 (64KB) aliases h tail
#define OFF_XCAT  10659328ull               // x_cat bf16: 2*163842*128*2 = 83887104 ; z1 aliases
#define OFF_Y     94546432ull               // y bf16: 2*163842*64*2 = 41943552
// total ≈ 136.5 MB

__device__ __forceinline__ void gload_lds16(const void* g, void* l) {
  __builtin_amdgcn_global_load_lds(
      (const __attribute__((address_space(1))) void*)g,
      (__attribute__((address_space(3))) void*)l, 16, 0, 0);
}

__device__ __forceinline__ float lrelu(float v) { return v >= 0.0f ? v : SLOPE * v; }

// ---------------- K0: permute + bf16-convert conv weights: f' = kk*C + c ----------------
__global__ __launch_bounds__(256) void k_permw(const float* __restrict__ w1,
                                               const float* __restrict__ w2,
                                               bf16* __restrict__ w1p, bf16* __restrict__ w2p) {
  int t = blockIdx.x * 256 + threadIdx.x;
  if (t < 64 * 896) {
    int o = t / 896, f = t % 896;
    int kk = f / 128, c = f % 128;
    w1p[t] = __float2bfloat16(w1[o * 896 + c * 7 + kk]);
  } else if (t < 64 * 896 + 64 * 448) {
    int idx = t - 64 * 896;
    int o = idx / 448, f = idx % 448;
    int kk = f / 64, c = f % 64;
    w2p[idx] = __float2bfloat16(w2[o * 448 + c * 7 + kk]);
  }
}

// ---------------- K1: h[b,n,o] = sum_c x1[b,c,n]*wfc[o,c] + bfc[o]  (bf16 out, node-major) ----
__global__ __launch_bounds__(256) void k_h(const float* __restrict__ x1,
                                           const float* __restrict__ wfc,
                                           const float* __restrict__ bfc,
                                           bf16* __restrict__ h) {
  __shared__ float wl[128 * 64];   // wl[c*64+o]
  __shared__ float bl[64];
  int tid = threadIdx.x, b = blockIdx.y;
  for (int i = tid; i < 8192; i += 256) { int o = i >> 7, c = i & 127; wl[c * 64 + o] = wfc[i]; }
  if (tid < 64) bl[tid] = bfc[tid];
  __syncthreads();
  int n = blockIdx.x * 256 + tid;
  int nc = n < ND ? n : ND - 1;
  float acc[64];
#pragma unroll
  for (int o = 0; o < 64; ++o) acc[o] = bl[o];
#pragma unroll 4
  for (int c = 0; c < 128; ++c) {
    float xv = x1[((size_t)b * 128 + c) * (size_t)ND + nc];
    const f32x4* wrow = (const f32x4*)(wl + c * 64);
#pragma unroll
    for (int og = 0; og < 16; ++og) {
      f32x4 wv = wrow[og];
      acc[og * 4 + 0] = fmaf(xv, wv[0], acc[og * 4 + 0]);
      acc[og * 4 + 1] = fmaf(xv, wv[1], acc[og * 4 + 1]);
      acc[og * 4 + 2] = fmaf(xv, wv[2], acc[og * 4 + 2]);
      acc[og * 4 + 3] = fmaf(xv, wv[3], acc[og * 4 + 3]);
    }
  }
  if (n < ND) {
    bf16* hp = h + ((size_t)b * ND + n) * 64;
#pragma unroll
    for (int og = 0; og < 8; ++og) {
      union { bf16x8 v; bf16 e[8]; } u;
#pragma unroll
      for (int j = 0; j < 8; ++j) u.e[j] = __float2bfloat16(acc[og * 8 + j]);
      ((bf16x8*)hp)[og] = u.v;
    }
  }
}

// ---------------- K2: x_cat[b,m,0:64] = 0.5*(h[n0]+h[n1]); x_cat[b,m,64:128] = x2[b,:,m] ------
__global__ __launch_bounds__(256) void k_xcat(const float* __restrict__ x2,
                                              const bf16* __restrict__ h,
                                              const int* __restrict__ upn,
                                              bf16* __restrict__ xcat) {
  __shared__ float tt[64][65];
  __shared__ int un[64][2];
  int tid = threadIdx.x, b = blockIdx.y;
  int m0 = blockIdx.x * 64;
#pragma unroll
  for (int i = 0; i < 16; ++i) {
    int c = i * 4 + (tid >> 6);
    int ml = tid & 63;
    int m = m0 + ml; if (m >= NUP) m = NUP - 1;
    tt[c][ml] = x2[((size_t)b * 64 + c) * (size_t)NUP + m];
  }
  if (tid < 128) {
    int ml = tid >> 1, w = tid & 1;
    int m = m0 + ml; if (m >= NUP) m = NUP - 1;
    un[ml][w] = upn[(size_t)m * 2 + w];
  }
  __syncthreads();
  int ln = tid >> 2, p = tid & 3;
  int m = m0 + ln;
  if (m >= NUP) return;
  bf16* dst = xcat + ((size_t)b * NUP + m) * 128;
  if (p < 2) {
    int c0 = p * 32;
    const bf16* h0 = h + ((size_t)b * ND + un[ln][0]) * 64 + c0;
    const bf16* h1 = h + ((size_t)b * ND + un[ln][1]) * 64 + c0;
#pragma unroll
    for (int q = 0; q < 4; ++q) {
      union { bf16x8 v; bf16 e[8]; } a, bb, o_;
      a.v = ((const bf16x8*)h0)[q];
      bb.v = ((const bf16x8*)h1)[q];
#pragma unroll
      for (int j = 0; j < 8; ++j)
        o_.e[j] = __float2bfloat16(0.5f * (__bfloat162float(a.e[j]) + __bfloat162float(bb.e[j])));
      ((bf16x8*)(dst + c0))[q] = o_.v;
    }
  } else {
    int c0 = (p - 2) * 32;
#pragma unroll
    for (int q = 0; q < 4; ++q) {
      union { bf16x8 v; bf16 e[8]; } o_;
#pragma unroll
      for (int j = 0; j < 8; ++j) o_.e[j] = __float2bfloat16(tt[c0 + q * 8 + j][ln]);
      ((bf16x8*)(dst + 64 + c0))[q] = o_.v;
    }
  }
}

// ---------------- K3: gathered conv (GEMM, K = 7*CIN), 2-phase dbuf A-staging, B direct ------
// r5 structure minus the W LDS tile: B-fragments read per kk straight from global (the 16KB
// permuted-W slice is shared by all blocks -> L1/L2-hot). LDS = 2x A-tile only:
// conv1 36.6KB -> 4 blocks/CU, conv2 20.6KB -> 7 blocks/CU. One __syncthreads per kk.
template <int CIN>
__global__ __launch_bounds__(256) void k_conv(const bf16* __restrict__ x,
                                              const int* __restrict__ neigh,
                                              const bf16* __restrict__ wp,
                                              const float* __restrict__ bias,
                                              bf16* __restrict__ y,
                                              float* __restrict__ partials) {
  constexpr int SLOTS = CIN / 8;             // 16B slots per row (16 or 8)
  constexpr int INSTR = (64 * CIN) / 512;    // 1KB DMA instrs per 64-row tile (16 or 8)
  constexpr int IPW   = INSTR / 4;           // DMA instrs per wave (4 or 2)
  constexpr int RPI   = 64 / INSTR;          // rows per DMA instr (4 or 8)
  constexpr int KS    = CIN / 32;            // MFMA K-steps per kk (4 or 2)
  constexpr int SWZ   = SLOTS - 1;

  __shared__ bf16 lA[2][64 * CIN];           // 2x16KB / 2x8KB
  __shared__ int nbl[448];
  __shared__ float lred[4][2][64];

  int tid = threadIdx.x, b = blockIdx.y;
  int n0 = blockIdx.x * 64;
  int wv = tid >> 6, lane = tid & 63;
  int l15 = lane & 15, l4 = lane >> 4;

  for (int j = tid; j < 448; j += 256) {
    int gi = n0 * 7 + j;
    int gmax = NUP * 7 - 1;
    nbl[j] = neigh[gi <= gmax ? gi : gmax];
  }

  f32x4 acc[4];
#pragma unroll
  for (int ot = 0; ot < 4; ++ot) {
    float bv = bias[ot * 16 + l15];
    acc[ot] = (f32x4){bv, bv, bv, bv};
  }

  const bf16* xb = x + (size_t)b * NUP * CIN;
  const int r_in = lane / SLOTS;             // row within DMA instr
  const int s_in = lane % SLOTS;             // 16B slot within row

  auto STAGE_A = [&](int buf, int kk) {
#pragma unroll
    for (int i = 0; i < IPW; ++i) {
      int ii = wv * IPW + i;
      int r = ii * RPI + r_in;
      int g = s_in ^ (r & SWZ);
      int node = nbl[r * 7 + kk];
      gload_lds16(xb + (size_t)node * CIN + g * 8, &lA[buf][ii * 512]);
    }
  };

  // per-lane W pointer: o = l15 (16 outs per colgroup), slot = l4
  const bf16* wl_ = wp + (size_t)l15 * (7 * CIN) + l4 * 8;

  __syncthreads();                           // nbl ready
  STAGE_A(0, 0);
  __syncthreads();                           // stage(0) complete (implicit vmcnt(0))

  for (int kk = 0; kk < 7; ++kk) {
    int buf = kk & 1;
    if (kk < 6) STAGE_A(buf ^ 1, kk + 1);
    // B fragments (kk) direct from global; L1/L2-hot
    bf16x8 bfr[4][KS];
#pragma unroll
    for (int ot = 0; ot < 4; ++ot)
#pragma unroll
      for (int ks = 0; ks < KS; ++ks)
        bfr[ot][ks] = *(const bf16x8*)(wl_ + (size_t)ot * (16 * 7 * CIN) + kk * CIN + ks * 32);
    // compute(kk): wave handles rows wv*16..+15, all 64 outs
    int r = wv * 16 + l15;
#pragma unroll
    for (int ks = 0; ks < KS; ++ks) {
      int sa = ks * 4 + l4;                  // k-slot index
      bf16x8 a = *(const bf16x8*)(&lA[buf][r * CIN + ((sa ^ (r & SWZ)) * 8)]);
#pragma unroll
      for (int ot = 0; ot < 4; ++ot)
        acc[ot] = __builtin_amdgcn_mfma_f32_16x16x32_bf16(a, bfr[ot][ks], acc[ot], 0, 0, 0);
    }
    __syncthreads();                         // drains stage(kk+1); releases buf for overwrite
  }

  // store y (bf16) + per-channel partial sums (valid nodes only)
  float s[4], q[4];
#pragma unroll
  for (int ot = 0; ot < 4; ++ot) { s[ot] = 0.0f; q[ot] = 0.0f; }
  bf16* yb = y + (size_t)b * NUP * 64;
  int nodebase = n0 + wv * 16 + l4 * 4;
#pragma unroll
  for (int i = 0; i < 4; ++i) {
    int node = nodebase + i;
    bool ok = node < NUP;
#pragma unroll
    for (int ot = 0; ot < 4; ++ot) {
      float v = acc[ot][i];
      if (ok) {
        yb[(size_t)node * 64 + ot * 16 + l15] = __float2bfloat16(v);
        s[ot] += v; q[ot] += v * v;
      }
    }
  }
#pragma unroll
  for (int ot = 0; ot < 4; ++ot) {
    s[ot] += __shfl_xor(s[ot], 16); s[ot] += __shfl_xor(s[ot], 32);
    q[ot] += __shfl_xor(q[ot], 16); q[ot] += __shfl_xor(q[ot], 32);
  }
  if (lane < 16) {
#pragma unroll
    for (int ot = 0; ot < 4; ++ot) {
      lred[wv][0][ot * 16 + lane] = s[ot];
      lred[wv][1][ot * 16 + lane] = q[ot];
    }
  }
  __syncthreads();
  if (tid < 128) {
    int which = tid >> 6, c = tid & 63;
    float p = lred[0][which][c] + lred[1][which][c] + lred[2][which][c] + lred[3][which][c];
    partials[((size_t)b * gridDim.x + blockIdx.x) * 128 + which * 64 + c] = p;
  }
}

// ---------------- K4a: tree-reduce partials (nblk x 128) -> (128 x 128) ----------------------
__global__ __launch_bounds__(256) void k_red1(const float* __restrict__ p, int nblk,
                                              float* __restrict__ p2) {
  int g = blockIdx.x * 2 + threadIdx.x / 128;
  int j = threadIdx.x & 127;
  float a = 0.0f;
  for (int r = g; r < nblk; r += 128) a += p[(size_t)r * 128 + j];
  p2[(size_t)g * 128 + j] = a;
}

// ---------------- K4b: finalize BN: sc = g*rsqrt(var+eps), sh = beta - mean*sc ---------------
__global__ __launch_bounds__(128) void k_stats(const float* __restrict__ p2,
                                               const float* __restrict__ g,
                                               const float* __restrict__ be,
                                               float* __restrict__ sc, float* __restrict__ sh) {
  __shared__ double red[128];
  int j = threadIdx.x;
  double a = 0.0;
  for (int r = 0; r < 128; ++r) a += (double)p2[r * 128 + j];
  red[j] = a;
  __syncthreads();
  if (j < 64) {
    double M = (double)NBATCH * (double)NUP;
    double mean = red[j] / M;
    double var = red[64 + j] / M - mean * mean;
    float s = g[j] * (float)(1.0 / sqrt(var + BN_EPS));
    sc[j] = s;
    sh[j] = be[j] - (float)mean * s;
  }
}

// ---------------- K5: z = bf16(lrelu(y*sc + sh))  (y bf16 node-major) ------------------------
__global__ __launch_bounds__(256) void k_bnapply(const bf16* __restrict__ y,
                                                 const float* __restrict__ sc,
                                                 const float* __restrict__ sh,
                                                 bf16* __restrict__ z) {
  __shared__ float ssc[64], ssh[64];
  int tid = threadIdx.x;
  if (tid < 64) { ssc[tid] = sc[tid]; ssh[tid] = sh[tid]; }
  __syncthreads();
  size_t e = ((size_t)blockIdx.x * 256 + tid) * 8;
  if (e >= (size_t)NBATCH * NUP * 64) return;
  int c0 = (int)(e & 63);
  union { bf16x8 v; bf16 el[8]; } in_, o_;
  in_.v = *(const bf16x8*)(y + e);
#pragma unroll
  for (int j = 0; j < 8; ++j) {
    float f = __bfloat162float(in_.el[j]);
    o_.el[j] = __float2bfloat16(lrelu(fmaf(f, ssc[c0 + j], ssh[c0 + j])));
  }
  *(bf16x8*)(z + e) = o_.v;
}

// ---------------- K8: out[b,c,n] = lrelu(y[b,n,c]*sc+sh)  (transpose to channel-major) -------
__global__ __launch_bounds__(256) void k_final(const bf16* __restrict__ y,
                                               const float* __restrict__ sc,
                                               const float* __restrict__ sh,
                                               float* __restrict__ out) {
  __shared__ float t[64][65];
  __shared__ float ssc[64], ssh[64];
  int tid = threadIdx.x, b = blockIdx.y;
  int n0 = blockIdx.x * 64;
  if (tid < 64) { ssc[tid] = sc[tid]; ssh[tid] = sh[tid]; }
  __syncthreads();
  int ln = tid >> 2, qc = tid & 3;
  int n = n0 + ln; if (n >= NUP) n = NUP - 1;
  const bf16* yp = y + ((size_t)b * NUP + n) * 64 + qc * 16;
  union { bf16x8 v; bf16 el[8]; } v0, v1;
  v0.v = ((const bf16x8*)yp)[0];
  v1.v = ((const bf16x8*)yp)[1];
#pragma unroll
  for (int j = 0; j < 8; ++j) {
    int c = qc * 16 + j;
    t[ln][c] = lrelu(fmaf(__bfloat162float(v0.el[j]), ssc[c], ssh[c]));
  }
#pragma unroll
  for (int j = 0; j < 8; ++j) {
    int c = qc * 16 + 8 + j;
    t[ln][c] = lrelu(fmaf(__bfloat162float(v1.el[j]), ssc[c], ssh[c]));
  }
  __syncthreads();
  int nl = tid & 63;
  int nn = n0 + nl;
  if (nn >= NUP) return;
#pragma unroll
  for (int i = 0; i < 16; ++i) {
    int c = i * 4 + (tid >> 6);
    out[((size_t)b * 64 + c) * (size_t)NUP + nn] = t[nl][c];
  }
}

extern "C" void kernel_launch(void* const* d_in, const int* in_sizes, int n_in,
                              void* d_out, int out_size, void* d_ws, size_t ws_size,
                              hipStream_t stream) {
  const float* x1      = (const float*)d_in[0];
  const float* x2      = (const float*)d_in[1];
  const float* up_fc_w = (const float*)d_in[2];
  const float* up_fc_b = (const float*)d_in[3];
  const float* conv1_w = (const float*)d_in[4];
  const float* conv1_b = (const float*)d_in[5];
  const float* bn1_g   = (const float*)d_in[6];
  const float* bn1_b   = (const float*)d_in[7];
  const float* conv2_w = (const float*)d_in[8];
  const float* conv2_b = (const float*)d_in[9];
  const float* bn2_g   = (const float*)d_in[10];
  const float* bn2_b   = (const float*)d_in[11];
  const int* up_neigh  = (const int*)d_in[12];
  const int* conv_nei  = (const int*)d_in[13];

  char* ws = (char*)d_ws;
  bf16*  w1p  = (bf16*)(ws + OFF_W1P);
  bf16*  w2p  = (bf16*)(ws + OFF_W2P);
  float* sc   = (float*)(ws + OFF_STATS);
  float* sh   = sc + 64;
  bf16*  h    = (bf16*)(ws + OFF_H);
  float* part = (float*)(ws + OFF_H);      // aliases h (h dead after k_xcat)
  float* p2   = (float*)(ws + OFF_P2);
  bf16*  xcat = (bf16*)(ws + OFF_XCAT);
  bf16*  z1   = (bf16*)(ws + OFF_XCAT);    // aliases xcat (dead after conv1)
  bf16*  y    = (bf16*)(ws + OFF_Y);
  float* out  = (float*)d_out;

  k_permw<<<336, 256, 0, stream>>>(conv1_w, conv2_w, w1p, w2p);
  k_h<<<dim3(161, 2), 256, 0, stream>>>(x1, up_fc_w, up_fc_b, h);
  k_xcat<<<dim3(NT64, 2), 256, 0, stream>>>(x2, h, up_neigh, xcat);
  k_conv<128><<<dim3(NTC, 2), 256, 0, stream>>>(xcat, conv_nei, w1p, conv1_b, y, part);
  k_red1<<<64, 256, 0, stream>>>(part, 2 * NTC, p2);
  k_stats<<<1, 128, 0, stream>>>(p2, bn1_g, bn1_b, sc, sh);
  k_bnapply<<<10241, 256, 0, stream>>>(y, sc, sh, z1);
  k_conv<64><<<dim3(NTC, 2), 256, 0, stream>>>(z1, conv_nei, w2p, conv2_b, y, part);
  k_red1<<<64, 256, 0, stream>>>(part, 2 * NTC, p2);
  k_stats<<<1, 128, 0, stream>>>(p2, bn2_g, bn2_b, sc, sh);
  k_final<<<dim3(NT64, 2), 256, 0, stream>>>(y, sc, sh, out);
}

// Round 7
// 353.234 us; speedup vs baseline: 1.7527x; 1.7527x over previous
//
#include <hip/hip_runtime.h>
#include <hip/hip_bf16.h>

typedef __hip_bfloat16 bf16;
typedef short bf16x8 __attribute__((ext_vector_type(8)));   // 8 bf16 = 16B (4 VGPRs)
typedef float f32x4 __attribute__((ext_vector_type(4)));

#define ND     40962
#define NUP    163842
#define NBATCH 2
#define NTC    2561            // ceil(NUP/64)  conv M-tiles (64 nodes/block)
#define NT64   2561
#define BN_EPS 1e-5
#define SLOPE  0.2f

// ---- ws layout (bytes), all 256-aligned ----
#define OFF_W1P   0ull                      // 64*896*2  = 114688
#define OFF_W2P   114688ull                 // 64*448*2  = 57344
#define OFF_STATS 172032ull                 // sc[64]+sh[64] fp32 = 512
#define OFF_H     173056ull                 // h bf16: 2*40962*64*2 = 10486272 ; partials alias
#define OFF_P2    (OFF_H + 2622464ull)      // p2 (64KB) aliases h tail
#define OFF_XCAT  10659328ull               // x_cat bf16: 2*163842*128*2 = 83887104 ; z1 aliases
#define OFF_Y     94546432ull               // y bf16: 2*163842*64*2 = 41943552
// total ≈ 136.5 MB

__device__ __forceinline__ void gload_lds16(const void* g, void* l) {
  __builtin_amdgcn_global_load_lds(
      (const __attribute__((address_space(1))) void*)g,
      (__attribute__((address_space(3))) void*)l, 16, 0, 0);
}

__device__ __forceinline__ float lrelu(float v) { return v >= 0.0f ? v : SLOPE * v; }

// ---------------- K0: permute + bf16-convert conv weights: f' = kk*C + c ----------------
__global__ __launch_bounds__(256) void k_permw(const float* __restrict__ w1,
                                               const float* __restrict__ w2,
                                               bf16* __restrict__ w1p, bf16* __restrict__ w2p) {
  int t = blockIdx.x * 256 + threadIdx.x;
  if (t < 64 * 896) {
    int o = t / 896, f = t % 896;
    int kk = f / 128, c = f % 128;
    w1p[t] = __float2bfloat16(w1[o * 896 + c * 7 + kk]);
  } else if (t < 64 * 896 + 64 * 448) {
    int idx = t - 64 * 896;
    int o = idx / 448, f = idx % 448;
    int kk = f / 64, c = f % 64;
    w2p[idx] = __float2bfloat16(w2[o * 448 + c * 7 + kk]);
  }
}

// ---------------- K1: h[b,n,o] = sum_c x1[b,c,n]*wfc[o,c] + bfc[o]  (bf16 out, node-major) ----
__global__ __launch_bounds__(256) void k_h(const float* __restrict__ x1,
                                           const float* __restrict__ wfc,
                                           const float* __restrict__ bfc,
                                           bf16* __restrict__ h) {
  __shared__ float wl[128 * 64];   // wl[c*64+o]
  __shared__ float bl[64];
  int tid = threadIdx.x, b = blockIdx.y;
  for (int i = tid; i < 8192; i += 256) { int o = i >> 7, c = i & 127; wl[c * 64 + o] = wfc[i]; }
  if (tid < 64) bl[tid] = bfc[tid];
  __syncthreads();
  int n = blockIdx.x * 256 + tid;
  int nc = n < ND ? n : ND - 1;
  float acc[64];
#pragma unroll
  for (int o = 0; o < 64; ++o) acc[o] = bl[o];
#pragma unroll 4
  for (int c = 0; c < 128; ++c) {
    float xv = x1[((size_t)b * 128 + c) * (size_t)ND + nc];
    const f32x4* wrow = (const f32x4*)(wl + c * 64);
#pragma unroll
    for (int og = 0; og < 16; ++og) {
      f32x4 wv = wrow[og];
      acc[og * 4 + 0] = fmaf(xv, wv[0], acc[og * 4 + 0]);
      acc[og * 4 + 1] = fmaf(xv, wv[1], acc[og * 4 + 1]);
      acc[og * 4 + 2] = fmaf(xv, wv[2], acc[og * 4 + 2]);
      acc[og * 4 + 3] = fmaf(xv, wv[3], acc[og * 4 + 3]);
    }
  }
  if (n < ND) {
    bf16* hp = h + ((size_t)b * ND + n) * 64;
#pragma unroll
    for (int og = 0; og < 8; ++og) {
      union { bf16x8 v; bf16 e[8]; } u;
#pragma unroll
      for (int j = 0; j < 8; ++j) u.e[j] = __float2bfloat16(acc[og * 8 + j]);
      ((bf16x8*)hp)[og] = u.v;
    }
  }
}

// ---------------- K2: x_cat[b,m,0:64] = 0.5*(h[n0]+h[n1]); x_cat[b,m,64:128] = x2[b,:,m] ------
__global__ __launch_bounds__(256) void k_xcat(const float* __restrict__ x2,
                                              const bf16* __restrict__ h,
                                              const int* __restrict__ upn,
                                              bf16* __restrict__ xcat) {
  __shared__ float tt[64][65];
  __shared__ int un[64][2];
  int tid = threadIdx.x, b = blockIdx.y;
  int m0 = blockIdx.x * 64;
#pragma unroll
  for (int i = 0; i < 16; ++i) {
    int c = i * 4 + (tid >> 6);
    int ml = tid & 63;
    int m = m0 + ml; if (m >= NUP) m = NUP - 1;
    tt[c][ml] = x2[((size_t)b * 64 + c) * (size_t)NUP + m];
  }
  if (tid < 128) {
    int ml = tid >> 1, w = tid & 1;
    int m = m0 + ml; if (m >= NUP) m = NUP - 1;
    un[ml][w] = upn[(size_t)m * 2 + w];
  }
  __syncthreads();
  int ln = tid >> 2, p = tid & 3;
  int m = m0 + ln;
  if (m >= NUP) return;
  bf16* dst = xcat + ((size_t)b * NUP + m) * 128;
  if (p < 2) {
    int c0 = p * 32;
    const bf16* h0 = h + ((size_t)b * ND + un[ln][0]) * 64 + c0;
    const bf16* h1 = h + ((size_t)b * ND + un[ln][1]) * 64 + c0;
#pragma unroll
    for (int q = 0; q < 4; ++q) {
      union { bf16x8 v; bf16 e[8]; } a, bb, o_;
      a.v = ((const bf16x8*)h0)[q];
      bb.v = ((const bf16x8*)h1)[q];
#pragma unroll
      for (int j = 0; j < 8; ++j)
        o_.e[j] = __float2bfloat16(0.5f * (__bfloat162float(a.e[j]) + __bfloat162float(bb.e[j])));
      ((bf16x8*)(dst + c0))[q] = o_.v;
    }
  } else {
    int c0 = (p - 2) * 32;
#pragma unroll
    for (int q = 0; q < 4; ++q) {
      union { bf16x8 v; bf16 e[8]; } o_;
#pragma unroll
      for (int j = 0; j < 8; ++j) o_.e[j] = __float2bfloat16(tt[c0 + q * 8 + j][ln]);
      ((bf16x8*)(dst + 64 + c0))[q] = o_.v;
    }
  }
}

// ---------------- K3: gathered conv — fine-grained 32-channel steps, max occupancy -----------
// Per step t=(kk,ks): stage A-tile 64 rows x 64B and W-tile 64 outs x 64B via global_load_lds
// into double buffers (4KB each). One __syncthreads per step (the only fence — the pattern
// every failed round violated). LDS ≈ 18KB -> 8 blocks/CU; __launch_bounds__(256,8) caps
// VGPR at 64 -> 32 waves/CU. Source-side slot swizzle g = s ^ ((row>>1)&3) with linear LDS
// dest makes A/W ds_read_b128 2-way (free). W slice (<=112KB) is L2-hot across all blocks.
template <int CIN>
__global__ __launch_bounds__(256, 8) void k_conv(const bf16* __restrict__ x,
                                                 const int* __restrict__ neigh,
                                                 const bf16* __restrict__ wp,
                                                 const float* __restrict__ bias,
                                                 bf16* __restrict__ y,
                                                 float* __restrict__ partials) {
  constexpr int KS    = CIN / 32;            // k-steps per neighbor (4 or 2)
  constexpr int NSTEP = 7 * KS;              // 28 or 14

  __shared__ bf16 lA[2][2048];               // [buf][row*32 + slot*8]  (64 rows x 64B)
  __shared__ bf16 lW[2][2048];               // [buf][out*32 + slot*8]
  __shared__ int nbl[448];

  int tid = threadIdx.x, b = blockIdx.y;
  int n0 = blockIdx.x * 64;
  int wv = tid >> 6, lane = tid & 63;
  int l15 = lane & 15, l4 = lane >> 4;

  for (int j = tid; j < 448; j += 256) {
    int gi = n0 * 7 + j;
    int gmax = NUP * 7 - 1;
    nbl[j] = neigh[gi <= gmax ? gi : gmax];
  }

  f32x4 acc[4];
#pragma unroll
  for (int ot = 0; ot < 4; ++ot) {
    float bv = bias[ot * 16 + l15];
    acc[ot] = (f32x4){bv, bv, bv, bv};
  }

  const bf16* xb = x + (size_t)b * NUP * CIN;
  // staging lane map: wave wv stages rows wv*16..+15; 4 lanes per row cover its 64B
  const int srow = wv * 16 + (lane >> 2);              // row / out index
  const int sg   = ((lane & 3) ^ ((srow >> 1) & 3)) * 8;  // pre-swizzled source slot (elems)
  const bf16* wrow_ = wp + (size_t)srow * (7 * CIN) + sg;

  auto STAGE = [&](int buf, int t) {
    int kk = t / KS, ks = t % KS;
    int node = nbl[srow * 7 + kk];
    gload_lds16(xb + (size_t)node * CIN + ks * 32 + sg, &lA[buf][wv * 512]);
    gload_lds16(wrow_ + kk * CIN + ks * 32, &lW[buf][wv * 512]);
  };

  // compute-side swizzled offsets (elems)
  const int r  = wv * 16 + l15;
  const int oa = r * 32 + ((l4 ^ ((l15 >> 1) & 3)) * 8);   // f(r)=f(l15) since wv*16≡0 mod 4

  __syncthreads();                           // nbl ready
  STAGE(0, 0);
  __syncthreads();                           // step 0 staged (implicit vmcnt(0))

  int buf = 0;
#pragma unroll
  for (int t = 0; t < NSTEP; ++t) {
    if (t + 1 < NSTEP) STAGE(buf ^ 1, t + 1);
    bf16x8 a = *(const bf16x8*)(&lA[buf][oa]);
#pragma unroll
    for (int ot = 0; ot < 4; ++ot) {
      int o = ot * 16 + l15;
      bf16x8 bb = *(const bf16x8*)(&lW[buf][o * 32 + ((l4 ^ ((l15 >> 1) & 3)) * 8)]);
      acc[ot] = __builtin_amdgcn_mfma_f32_16x16x32_bf16(a, bb, acc[ot], 0, 0, 0);
    }
    __syncthreads();                         // drains stage(t+1); releases buf
    buf ^= 1;
  }

  // store y (bf16) + per-channel partial sums (valid nodes only)
  float* lred = (float*)&lA[0][0];           // alias staging LDS (dead after K-loop)
  float s[4], q[4];
#pragma unroll
  for (int ot = 0; ot < 4; ++ot) { s[ot] = 0.0f; q[ot] = 0.0f; }
  bf16* yb = y + (size_t)b * NUP * 64;
  int nodebase = n0 + wv * 16 + l4 * 4;
#pragma unroll
  for (int i = 0; i < 4; ++i) {
    int node = nodebase + i;
    bool ok = node < NUP;
#pragma unroll
    for (int ot = 0; ot < 4; ++ot) {
      float v = acc[ot][i];
      if (ok) {
        yb[(size_t)node * 64 + ot * 16 + l15] = __float2bfloat16(v);
        s[ot] += v; q[ot] += v * v;
      }
    }
  }
#pragma unroll
  for (int ot = 0; ot < 4; ++ot) {
    s[ot] += __shfl_xor(s[ot], 16); s[ot] += __shfl_xor(s[ot], 32);
    q[ot] += __shfl_xor(q[ot], 16); q[ot] += __shfl_xor(q[ot], 32);
  }
  if (lane < 16) {
#pragma unroll
    for (int ot = 0; ot < 4; ++ot) {
      lred[(wv * 2 + 0) * 64 + ot * 16 + lane] = s[ot];
      lred[(wv * 2 + 1) * 64 + ot * 16 + lane] = q[ot];
    }
  }
  __syncthreads();
  if (tid < 128) {
    int which = tid >> 6, c = tid & 63;
    float p = lred[(0 * 2 + which) * 64 + c] + lred[(1 * 2 + which) * 64 + c] +
              lred[(2 * 2 + which) * 64 + c] + lred[(3 * 2 + which) * 64 + c];
    partials[((size_t)b * gridDim.x + blockIdx.x) * 128 + which * 64 + c] = p;
  }
}

// ---------------- K4a: tree-reduce partials (nblk x 128) -> (128 x 128) ----------------------
__global__ __launch_bounds__(256) void k_red1(const float* __restrict__ p, int nblk,
                                              float* __restrict__ p2) {
  int g = blockIdx.x * 2 + threadIdx.x / 128;
  int j = threadIdx.x & 127;
  float a = 0.0f;
  for (int r = g; r < nblk; r += 128) a += p[(size_t)r * 128 + j];
  p2[(size_t)g * 128 + j] = a;
}

// ---------------- K4b: finalize BN: sc = g*rsqrt(var+eps), sh = beta - mean*sc ---------------
__global__ __launch_bounds__(128) void k_stats(const float* __restrict__ p2,
                                               const float* __restrict__ g,
                                               const float* __restrict__ be,
                                               float* __restrict__ sc, float* __restrict__ sh) {
  __shared__ double red[128];
  int j = threadIdx.x;
  double a = 0.0;
  for (int r = 0; r < 128; ++r) a += (double)p2[r * 128 + j];
  red[j] = a;
  __syncthreads();
  if (j < 64) {
    double M = (double)NBATCH * (double)NUP;
    double mean = red[j] / M;
    double var = red[64 + j] / M - mean * mean;
    float s = g[j] * (float)(1.0 / sqrt(var + BN_EPS));
    sc[j] = s;
    sh[j] = be[j] - (float)mean * s;
  }
}

// ---------------- K5: z = bf16(lrelu(y*sc + sh))  (y bf16 node-major) ------------------------
__global__ __launch_bounds__(256) void k_bnapply(const bf16* __restrict__ y,
                                                 const float* __restrict__ sc,
                                                 const float* __restrict__ sh,
                                                 bf16* __restrict__ z) {
  __shared__ float ssc[64], ssh[64];
  int tid = threadIdx.x;
  if (tid < 64) { ssc[tid] = sc[tid]; ssh[tid] = sh[tid]; }
  __syncthreads();
  size_t e = ((size_t)blockIdx.x * 256 + tid) * 8;
  if (e >= (size_t)NBATCH * NUP * 64) return;
  int c0 = (int)(e & 63);
  union { bf16x8 v; bf16 el[8]; } in_, o_;
  in_.v = *(const bf16x8*)(y + e);
#pragma unroll
  for (int j = 0; j < 8; ++j) {
    float f = __bfloat162float(in_.el[j]);
    o_.el[j] = __float2bfloat16(lrelu(fmaf(f, ssc[c0 + j], ssh[c0 + j])));
  }
  *(bf16x8*)(z + e) = o_.v;
}

// ---------------- K8: out[b,c,n] = lrelu(y[b,n,c]*sc+sh)  (transpose to channel-major) -------
__global__ __launch_bounds__(256) void k_final(const bf16* __restrict__ y,
                                               const float* __restrict__ sc,
                                               const float* __restrict__ sh,
                                               float* __restrict__ out) {
  __shared__ float t[64][65];
  __shared__ float ssc[64], ssh[64];
  int tid = threadIdx.x, b = blockIdx.y;
  int n0 = blockIdx.x * 64;
  if (tid < 64) { ssc[tid] = sc[tid]; ssh[tid] = sh[tid]; }
  __syncthreads();
  int ln = tid >> 2, qc = tid & 3;
  int n = n0 + ln; if (n >= NUP) n = NUP - 1;
  const bf16* yp = y + ((size_t)b * NUP + n) * 64 + qc * 16;
  union { bf16x8 v; bf16 el[8]; } v0, v1;
  v0.v = ((const bf16x8*)yp)[0];
  v1.v = ((const bf16x8*)yp)[1];
#pragma unroll
  for (int j = 0; j < 8; ++j) {
    int c = qc * 16 + j;
    t[ln][c] = lrelu(fmaf(__bfloat162float(v0.el[j]), ssc[c], ssh[c]));
  }
#pragma unroll
  for (int j = 0; j < 8; ++j) {
    int c = qc * 16 + 8 + j;
    t[ln][c] = lrelu(fmaf(__bfloat162float(v1.el[j]), ssc[c], ssh[c]));
  }
  __syncthreads();
  int nl = tid & 63;
  int nn = n0 + nl;
  if (nn >= NUP) return;
#pragma unroll
  for (int i = 0; i < 16; ++i) {
    int c = i * 4 + (tid >> 6);
    out[((size_t)b * 64 + c) * (size_t)NUP + nn] = t[nl][c];
  }
}

extern "C" void kernel_launch(void* const* d_in, const int* in_sizes, int n_in,
                              void* d_out, int out_size, void* d_ws, size_t ws_size,
                              hipStream_t stream) {
  const float* x1      = (const float*)d_in[0];
  const float* x2      = (const float*)d_in[1];
  const float* up_fc_w = (const float*)d_in[2];
  const float* up_fc_b = (const float*)d_in[3];
  const float* conv1_w = (const float*)d_in[4];
  const float* conv1_b = (const float*)d_in[5];
  const float* bn1_g   = (const float*)d_in[6];
  const float* bn1_b   = (const float*)d_in[7];
  const float* conv2_w = (const float*)d_in[8];
  const float* conv2_b = (const float*)d_in[9];
  const float* bn2_g   = (const float*)d_in[10];
  const float* bn2_b   = (const float*)d_in[11];
  const int* up_neigh  = (const int*)d_in[12];
  const int* conv_nei  = (const int*)d_in[13];

  char* ws = (char*)d_ws;
  bf16*  w1p  = (bf16*)(ws + OFF_W1P);
  bf16*  w2p  = (bf16*)(ws + OFF_W2P);
  float* sc   = (float*)(ws + OFF_STATS);
  float* sh   = sc + 64;
  bf16*  h    = (bf16*)(ws + OFF_H);
  float* part = (float*)(ws + OFF_H);      // aliases h (h dead after k_xcat)
  float* p2   = (float*)(ws + OFF_P2);
  bf16*  xcat = (bf16*)(ws + OFF_XCAT);
  bf16*  z1   = (bf16*)(ws + OFF_XCAT);    // aliases xcat (dead after conv1)
  bf16*  y    = (bf16*)(ws + OFF_Y);
  float* out  = (float*)d_out;

  k_permw<<<336, 256, 0, stream>>>(conv1_w, conv2_w, w1p, w2p);
  k_h<<<dim3(161, 2), 256, 0, stream>>>(x1, up_fc_w, up_fc_b, h);
  k_xcat<<<dim3(NT64, 2), 256, 0, stream>>>(x2, h, up_neigh, xcat);
  k_conv<128><<<dim3(NTC, 2), 256, 0, stream>>>(xcat, conv_nei, w1p, conv1_b, y, part);
  k_red1<<<64, 256, 0, stream>>>(part, 2 * NTC, p2);
  k_stats<<<1, 128, 0, stream>>>(p2, bn1_g, bn1_b, sc, sh);
  k_bnapply<<<10241, 256, 0, stream>>>(y, sc, sh, z1);
  k_conv<64><<<dim3(NTC, 2), 256, 0, stream>>>(z1, conv_nei, w2p, conv2_b, y, part);
  k_red1<<<64, 256, 0, stream>>>(part, 2 * NTC, p2);
  k_stats<<<1, 128, 0, stream>>>(p2, bn2_g, bn2_b, sc, sh);
  k_final<<<dim3(NT64, 2), 256, 0, stream>>>(y, sc, sh, out);
}

// Round 8
// 336.477 us; speedup vs baseline: 1.8400x; 1.0498x over previous
//
#include <hip/hip_runtime.h>
#include <hip/hip_bf16.h>

typedef __hip_bfloat16 bf16;
typedef short bf16x8 __attribute__((ext_vector_type(8)));   // 8 bf16 = 16B (4 VGPRs)
typedef float f32x4 __attribute__((ext_vector_type(4)));

#define ND     40962
#define NUP    163842
#define NBATCH 2
#define NTC    2561            // ceil(NUP/64)
#define BN_EPS 1e-5
#define SLOPE  0.2f

// ---- ws layout (bytes) ----
#define OFF_W1P   0ull                      // 64*896*2  = 114688
#define OFF_W2P   114688ull                 // 64*448*2  = 57344
#define OFF_STATS 172032ull                 // sc[64]+sh[64] fp32
#define OFF_H     173056ull                 // h bf16: 2*40962*64*2 = 10486272 ; partials alias
#define OFF_P2    (OFF_H + 2622464ull)      // p2 (64KB) aliases h tail
#define OFF_HM    10659328ull               // hm bf16: 2*163842*64*2 = 41943552 ; y2 aliases
#define OFF_X2T   52602880ull               // x2t bf16: 41943552
#define OFF_Y     94546432ull               // y bf16: 41943552
// total ≈ 136.5 MB

__device__ __forceinline__ void gload_lds16(const void* g, void* l) {
  __builtin_amdgcn_global_load_lds(
      (const __attribute__((address_space(1))) void*)g,
      (__attribute__((address_space(3))) void*)l, 16, 0, 0);
}

__device__ __forceinline__ float lrelu(float v) { return v >= 0.0f ? v : SLOPE * v; }

// ---------------- K0: permute + bf16-convert conv weights: f' = kk*C + c ----------------
__global__ __launch_bounds__(256) void k_permw(const float* __restrict__ w1,
                                               const float* __restrict__ w2,
                                               bf16* __restrict__ w1p, bf16* __restrict__ w2p) {
  int t = blockIdx.x * 256 + threadIdx.x;
  if (t < 64 * 896) {
    int o = t / 896, f = t % 896;
    int kk = f / 128, c = f % 128;
    w1p[t] = __float2bfloat16(w1[o * 896 + c * 7 + kk]);
  } else if (t < 64 * 896 + 64 * 448) {
    int idx = t - 64 * 896;
    int o = idx / 448, f = idx % 448;
    int kk = f / 64, c = f % 64;
    w2p[idx] = __float2bfloat16(w2[o * 448 + c * 7 + kk]);
  }
}

// ---------------- K1: h[b,n,o] = sum_c x1[b,c,n]*wfc[o,c] + bfc[o]  (bf16, node-major) -------
__global__ __launch_bounds__(256) void k_h(const float* __restrict__ x1,
                                           const float* __restrict__ wfc,
                                           const float* __restrict__ bfc,
                                           bf16* __restrict__ h) {
  __shared__ float wl[128 * 64];
  __shared__ float bl[64];
  int tid = threadIdx.x, b = blockIdx.y;
  for (int i = tid; i < 8192; i += 256) { int o = i >> 7, c = i & 127; wl[c * 64 + o] = wfc[i]; }
  if (tid < 64) bl[tid] = bfc[tid];
  __syncthreads();
  int n = blockIdx.x * 256 + tid;
  int nc = n < ND ? n : ND - 1;
  float acc[64];
#pragma unroll
  for (int o = 0; o < 64; ++o) acc[o] = bl[o];
#pragma unroll 4
  for (int c = 0; c < 128; ++c) {
    float xv = x1[((size_t)b * 128 + c) * (size_t)ND + nc];
    const f32x4* wrow = (const f32x4*)(wl + c * 64);
#pragma unroll
    for (int og = 0; og < 16; ++og) {
      f32x4 wv = wrow[og];
      acc[og * 4 + 0] = fmaf(xv, wv[0], acc[og * 4 + 0]);
      acc[og * 4 + 1] = fmaf(xv, wv[1], acc[og * 4 + 1]);
      acc[og * 4 + 2] = fmaf(xv, wv[2], acc[og * 4 + 2]);
      acc[og * 4 + 3] = fmaf(xv, wv[3], acc[og * 4 + 3]);
    }
  }
  if (n < ND) {
    bf16* hp = h + ((size_t)b * ND + n) * 64;
#pragma unroll
    for (int og = 0; og < 8; ++og) {
      union { bf16x8 v; bf16 e[8]; } u;
#pragma unroll
      for (int j = 0; j < 8; ++j) u.e[j] = __float2bfloat16(acc[og * 8 + j]);
      ((bf16x8*)hp)[og] = u.v;
    }
  }
}

// ---------------- K2a: hm[b,m,:] = 0.5*(h[up0]+h[up1])  (h is L2/L3-resident, 10.5MB) --------
__global__ __launch_bounds__(256) void k_hm(const bf16* __restrict__ h,
                                            const int* __restrict__ upn,
                                            bf16* __restrict__ hm) {
  __shared__ int un[64][2];
  int tid = threadIdx.x, b = blockIdx.y;
  int m0 = blockIdx.x * 64;
  if (tid < 128) {
    int ml = tid >> 1, w = tid & 1;
    int m = m0 + ml; if (m >= NUP) m = NUP - 1;
    un[ml][w] = upn[(size_t)m * 2 + w];
  }
  __syncthreads();
  int ln = tid >> 2, sg = tid & 3;
  int m = m0 + ln;
  if (m >= NUP) return;
  const bf16* h0 = h + ((size_t)b * ND + un[ln][0]) * 64 + sg * 16;
  const bf16* h1 = h + ((size_t)b * ND + un[ln][1]) * 64 + sg * 16;
  bf16* d = hm + ((size_t)b * NUP + m) * 64 + sg * 16;
#pragma unroll
  for (int q = 0; q < 2; ++q) {
    union { bf16x8 v; bf16 e[8]; } a, bb, o_;
    a.v = ((const bf16x8*)h0)[q];
    bb.v = ((const bf16x8*)h1)[q];
#pragma unroll
    for (int j = 0; j < 8; ++j)
      o_.e[j] = __float2bfloat16(0.5f * (__bfloat162float(a.e[j]) + __bfloat162float(bb.e[j])));
    ((bf16x8*)d)[q] = o_.v;
  }
}

// ---------------- K2b: x2t[b,m,c] = bf16(x2[b,c,m])  (transpose to node-major) ---------------
__global__ __launch_bounds__(256) void k_x2t(const float* __restrict__ x2,
                                             bf16* __restrict__ x2t) {
  __shared__ float tt[64][65];
  int tid = threadIdx.x, b = blockIdx.y;
  int m0 = blockIdx.x * 64;
#pragma unroll
  for (int i = 0; i < 16; ++i) {
    int c = i * 4 + (tid >> 6);
    int ml = tid & 63;
    int m = m0 + ml; if (m >= NUP) m = NUP - 1;
    tt[c][ml] = x2[((size_t)b * 64 + c) * (size_t)NUP + m];
  }
  __syncthreads();
  int ln = tid >> 2, sg = tid & 3;
  int m = m0 + ln;
  if (m >= NUP) return;
  bf16* d = x2t + ((size_t)b * NUP + m) * 64 + sg * 16;
#pragma unroll
  for (int q = 0; q < 2; ++q) {
    union { bf16x8 v; bf16 e[8]; } o_;
#pragma unroll
    for (int j = 0; j < 8; ++j) o_.e[j] = __float2bfloat16(tt[sg * 16 + q * 8 + j][ln]);
    ((bf16x8*)d)[q] = o_.v;
  }
}

// ---------------- K3: conv1 — r7 step structure; A source = hm (ks 0,1) / x2t (ks 2,3) -------
__global__ __launch_bounds__(256, 8) void k_conv1(const bf16* __restrict__ hm,
                                                  const bf16* __restrict__ x2t,
                                                  const int* __restrict__ neigh,
                                                  const bf16* __restrict__ wp,
                                                  const float* __restrict__ bias,
                                                  bf16* __restrict__ y,
                                                  float* __restrict__ partials) {
  constexpr int NSTEP = 28;                 // 7 kk x 4 ks (32ch each)
  __shared__ bf16 lA[2][2048];
  __shared__ bf16 lW[2][2048];
  __shared__ int nbl[448];

  int tid = threadIdx.x, b = blockIdx.y;
  int n0 = blockIdx.x * 64;
  int wv = tid >> 6, lane = tid & 63;
  int l15 = lane & 15, l4 = lane >> 4;

  for (int j = tid; j < 448; j += 256) {
    int gi = n0 * 7 + j;
    int gmax = NUP * 7 - 1;
    nbl[j] = neigh[gi <= gmax ? gi : gmax];
  }

  f32x4 acc[4];
#pragma unroll
  for (int ot = 0; ot < 4; ++ot) {
    float bv = bias[ot * 16 + l15];
    acc[ot] = (f32x4){bv, bv, bv, bv};
  }

  const bf16* hmb  = hm  + (size_t)b * NUP * 64;
  const bf16* x2tb = x2t + (size_t)b * NUP * 64;
  const int srow = wv * 16 + (lane >> 2);
  const int sg   = ((lane & 3) ^ ((srow >> 1) & 3)) * 8;   // pre-swizzled source offset
  const bf16* wrow_ = wp + (size_t)srow * 896 + sg;

  auto STAGE = [&](int buf, int t) {
    int kk = t >> 2, ks = t & 3;
    int node = nbl[srow * 7 + kk];
    const bf16* src = (ks < 2) ? (hmb + (size_t)node * 64 + ks * 32)
                               : (x2tb + (size_t)node * 64 + (ks - 2) * 32);
    gload_lds16(src + sg, &lA[buf][wv * 512]);
    gload_lds16(wrow_ + kk * 128 + ks * 32, &lW[buf][wv * 512]);
  };

  const int r  = wv * 16 + l15;
  const int oa = r * 32 + ((l4 ^ ((l15 >> 1) & 3)) * 8);

  __syncthreads();                           // nbl ready
  STAGE(0, 0);
  __syncthreads();                           // step 0 staged

  int buf = 0;
#pragma unroll
  for (int t = 0; t < NSTEP; ++t) {
    if (t + 1 < NSTEP) STAGE(buf ^ 1, t + 1);
    bf16x8 a = *(const bf16x8*)(&lA[buf][oa]);
#pragma unroll
    for (int ot = 0; ot < 4; ++ot) {
      int o = ot * 16 + l15;
      bf16x8 bb = *(const bf16x8*)(&lW[buf][o * 32 + ((l4 ^ ((l15 >> 1) & 3)) * 8)]);
      acc[ot] = __builtin_amdgcn_mfma_f32_16x16x32_bf16(a, bb, acc[ot], 0, 0, 0);
    }
    __syncthreads();
    buf ^= 1;
  }

  float* lred = (float*)&lA[0][0];
  float s[4], q[4];
#pragma unroll
  for (int ot = 0; ot < 4; ++ot) { s[ot] = 0.0f; q[ot] = 0.0f; }
  bf16* yb = y + (size_t)b * NUP * 64;
  int nodebase = n0 + wv * 16 + l4 * 4;
#pragma unroll
  for (int i = 0; i < 4; ++i) {
    int node = nodebase + i;
    bool ok = node < NUP;
#pragma unroll
    for (int ot = 0; ot < 4; ++ot) {
      float v = acc[ot][i];
      if (ok) {
        yb[(size_t)node * 64 + ot * 16 + l15] = __float2bfloat16(v);
        s[ot] += v; q[ot] += v * v;
      }
    }
  }
#pragma unroll
  for (int ot = 0; ot < 4; ++ot) {
    s[ot] += __shfl_xor(s[ot], 16); s[ot] += __shfl_xor(s[ot], 32);
    q[ot] += __shfl_xor(q[ot], 16); q[ot] += __shfl_xor(q[ot], 32);
  }
  if (lane < 16) {
#pragma unroll
    for (int ot = 0; ot < 4; ++ot) {
      lred[(wv * 2 + 0) * 64 + ot * 16 + lane] = s[ot];
      lred[(wv * 2 + 1) * 64 + ot * 16 + lane] = q[ot];
    }
  }
  __syncthreads();
  if (tid < 128) {
    int which = tid >> 6, c = tid & 63;
    float p = lred[(0 * 2 + which) * 64 + c] + lred[(1 * 2 + which) * 64 + c] +
              lred[(2 * 2 + which) * 64 + c] + lred[(3 * 2 + which) * 64 + c];
    partials[((size_t)b * gridDim.x + blockIdx.x) * 128 + which * 64 + c] = p;
  }
}

// ---------------- K5: conv2 — BN1+lrelu fused into reg-staged A gather of y ------------------
// Per step: W via DMA; A rows loaded to VGPRs in the STAGE phase (drained by the barrier's
// vmcnt(0) for free), BN+lrelu+ds_write AFTER the barrier (A rows are wave-private).
__global__ __launch_bounds__(256, 8) void k_conv2(const bf16* __restrict__ y,
                                                  const int* __restrict__ neigh,
                                                  const bf16* __restrict__ wp,
                                                  const float* __restrict__ bias,
                                                  const float* __restrict__ sc,
                                                  const float* __restrict__ sh,
                                                  bf16* __restrict__ y2,
                                                  float* __restrict__ partials) {
  constexpr int NSTEP = 14;                 // 7 kk x 2 ks
  __shared__ bf16 lA[2][2048];
  __shared__ bf16 lW[2][2048];
  __shared__ int nbl[448];
  __shared__ float ssc[64], ssh[64];

  int tid = threadIdx.x, b = blockIdx.y;
  int n0 = blockIdx.x * 64;
  int wv = tid >> 6, lane = tid & 63;
  int l15 = lane & 15, l4 = lane >> 4;

  for (int j = tid; j < 448; j += 256) {
    int gi = n0 * 7 + j;
    int gmax = NUP * 7 - 1;
    nbl[j] = neigh[gi <= gmax ? gi : gmax];
  }
  if (tid < 64) { ssc[tid] = sc[tid]; ssh[tid] = sh[tid]; }

  f32x4 acc[4];
#pragma unroll
  for (int ot = 0; ot < 4; ++ot) {
    float bv = bias[ot * 16 + l15];
    acc[ot] = (f32x4){bv, bv, bv, bv};
  }

  const bf16* yb = y + (size_t)b * NUP * 64;
  const int srow = wv * 16 + (lane >> 2);
  const int seg  = lane & 3;
  const int slot = (seg ^ ((srow >> 1) & 3)) * 8;          // swizzled LDS slot (elems)
  const bf16* wrow_ = wp + (size_t)srow * 448 + slot;

  bf16x8 anext;
  auto STAGE_W = [&](int buf, int t) {
    int kk = t >> 1, ks = t & 1;
    gload_lds16(wrow_ + kk * 64 + ks * 32, &lW[buf][wv * 512]);
  };
  auto ALOAD = [&](int t) {
    int kk = t >> 1, ks = t & 1;
    int node = nbl[srow * 7 + kk];
    anext = *(const bf16x8*)(yb + (size_t)node * 64 + ks * 32 + seg * 8);
  };
  auto BNW = [&](int buf, int t) {
    int ks = t & 1;
    union { bf16x8 v; bf16 e[8]; } u, o_;
    u.v = anext;
#pragma unroll
    for (int j = 0; j < 8; ++j) {
      int c = ks * 32 + seg * 8 + j;
      float f = __bfloat162float(u.e[j]);
      o_.e[j] = __float2bfloat16(lrelu(fmaf(f, ssc[c], ssh[c])));
    }
    *(bf16x8*)(&lA[buf][srow * 32 + slot]) = o_.v;
  };

  const int r  = wv * 16 + l15;
  const int oa = r * 32 + ((l4 ^ ((l15 >> 1) & 3)) * 8);

  __syncthreads();                           // nbl, ssc ready
  STAGE_W(0, 0); ALOAD(0);
  __syncthreads();                           // W(0) staged, A(0) loads drained
  BNW(0, 0);

  int buf = 0;
#pragma unroll
  for (int t = 0; t < NSTEP; ++t) {
    if (t + 1 < NSTEP) { STAGE_W(buf ^ 1, t + 1); ALOAD(t + 1); }
    bf16x8 a = *(const bf16x8*)(&lA[buf][oa]);
#pragma unroll
    for (int ot = 0; ot < 4; ++ot) {
      int o = ot * 16 + l15;
      bf16x8 bb = *(const bf16x8*)(&lW[buf][o * 32 + ((l4 ^ ((l15 >> 1) & 3)) * 8)]);
      acc[ot] = __builtin_amdgcn_mfma_f32_16x16x32_bf16(a, bb, acc[ot], 0, 0, 0);
    }
    __syncthreads();
    if (t + 1 < NSTEP) BNW(buf ^ 1, t + 1);
    buf ^= 1;
  }

  float* lred = (float*)&lA[0][0];
  float s[4], q[4];
#pragma unroll
  for (int ot = 0; ot < 4; ++ot) { s[ot] = 0.0f; q[ot] = 0.0f; }
  bf16* yo = y2 + (size_t)b * NUP * 64;
  int nodebase = n0 + wv * 16 + l4 * 4;
#pragma unroll
  for (int i = 0; i < 4; ++i) {
    int node = nodebase + i;
    bool ok = node < NUP;
#pragma unroll
    for (int ot = 0; ot < 4; ++ot) {
      float v = acc[ot][i];
      if (ok) {
        yo[(size_t)node * 64 + ot * 16 + l15] = __float2bfloat16(v);
        s[ot] += v; q[ot] += v * v;
      }
    }
  }
#pragma unroll
  for (int ot = 0; ot < 4; ++ot) {
    s[ot] += __shfl_xor(s[ot], 16); s[ot] += __shfl_xor(s[ot], 32);
    q[ot] += __shfl_xor(q[ot], 16); q[ot] += __shfl_xor(q[ot], 32);
  }
  if (lane < 16) {
#pragma unroll
    for (int ot = 0; ot < 4; ++ot) {
      lred[(wv * 2 + 0) * 64 + ot * 16 + lane] = s[ot];
      lred[(wv * 2 + 1) * 64 + ot * 16 + lane] = q[ot];
    }
  }
  __syncthreads();
  if (tid < 128) {
    int which = tid >> 6, c = tid & 63;
    float p = lred[(0 * 2 + which) * 64 + c] + lred[(1 * 2 + which) * 64 + c] +
              lred[(2 * 2 + which) * 64 + c] + lred[(3 * 2 + which) * 64 + c];
    partials[((size_t)b * gridDim.x + blockIdx.x) * 128 + which * 64 + c] = p;
  }
}

// ---------------- K4a: tree-reduce partials (nblk x 128) -> (128 x 128) ----------------------
__global__ __launch_bounds__(256) void k_red1(const float* __restrict__ p, int nblk,
                                              float* __restrict__ p2) {
  int g = blockIdx.x * 2 + threadIdx.x / 128;
  int j = threadIdx.x & 127;
  float a = 0.0f;
  for (int r = g; r < nblk; r += 128) a += p[(size_t)r * 128 + j];
  p2[(size_t)g * 128 + j] = a;
}

// ---------------- K4b: finalize BN: sc = g*rsqrt(var+eps), sh = beta - mean*sc ---------------
__global__ __launch_bounds__(128) void k_stats(const float* __restrict__ p2,
                                               const float* __restrict__ g,
                                               const float* __restrict__ be,
                                               float* __restrict__ sc, float* __restrict__ sh) {
  __shared__ double red[128];
  int j = threadIdx.x;
  double a = 0.0;
  for (int r = 0; r < 128; ++r) a += (double)p2[r * 128 + j];
  red[j] = a;
  __syncthreads();
  if (j < 64) {
    double M = (double)NBATCH * (double)NUP;
    double mean = red[j] / M;
    double var = red[64 + j] / M - mean * mean;
    float s = g[j] * (float)(1.0 / sqrt(var + BN_EPS));
    sc[j] = s;
    sh[j] = be[j] - (float)mean * s;
  }
}

// ---------------- K8: out[b,c,n] = lrelu(y2[b,n,c]*sc+sh)  (transpose to channel-major) ------
__global__ __launch_bounds__(256) void k_final(const bf16* __restrict__ y,
                                               const float* __restrict__ sc,
                                               const float* __restrict__ sh,
                                               float* __restrict__ out) {
  __shared__ float t[64][65];
  __shared__ float ssc[64], ssh[64];
  int tid = threadIdx.x, b = blockIdx.y;
  int n0 = blockIdx.x * 64;
  if (tid < 64) { ssc[tid] = sc[tid]; ssh[tid] = sh[tid]; }
  __syncthreads();
  int ln = tid >> 2, qc = tid & 3;
  int n = n0 + ln; if (n >= NUP) n = NUP - 1;
  const bf16* yp = y + ((size_t)b * NUP + n) * 64 + qc * 16;
  union { bf16x8 v; bf16 el[8]; } v0, v1;
  v0.v = ((const bf16x8*)yp)[0];
  v1.v = ((const bf16x8*)yp)[1];
#pragma unroll
  for (int j = 0; j < 8; ++j) {
    int c = qc * 16 + j;
    t[ln][c] = lrelu(fmaf(__bfloat162float(v0.el[j]), ssc[c], ssh[c]));
  }
#pragma unroll
  for (int j = 0; j < 8; ++j) {
    int c = qc * 16 + 8 + j;
    t[ln][c] = lrelu(fmaf(__bfloat162float(v1.el[j]), ssc[c], ssh[c]));
  }
  __syncthreads();
  int nl = tid & 63;
  int nn = n0 + nl;
  if (nn >= NUP) return;
#pragma unroll
  for (int i = 0; i < 16; ++i) {
    int c = i * 4 + (tid >> 6);
    out[((size_t)b * 64 + c) * (size_t)NUP + nn] = t[nl][c];
  }
}

extern "C" void kernel_launch(void* const* d_in, const int* in_sizes, int n_in,
                              void* d_out, int out_size, void* d_ws, size_t ws_size,
                              hipStream_t stream) {
  const float* x1      = (const float*)d_in[0];
  const float* x2      = (const float*)d_in[1];
  const float* up_fc_w = (const float*)d_in[2];
  const float* up_fc_b = (const float*)d_in[3];
  const float* conv1_w = (const float*)d_in[4];
  const float* conv1_b = (const float*)d_in[5];
  const float* bn1_g   = (const float*)d_in[6];
  const float* bn1_b   = (const float*)d_in[7];
  const float* conv2_w = (const float*)d_in[8];
  const float* conv2_b = (const float*)d_in[9];
  const float* bn2_g   = (const float*)d_in[10];
  const float* bn2_b   = (const float*)d_in[11];
  const int* up_neigh  = (const int*)d_in[12];
  const int* conv_nei  = (const int*)d_in[13];

  char* ws = (char*)d_ws;
  bf16*  w1p  = (bf16*)(ws + OFF_W1P);
  bf16*  w2p  = (bf16*)(ws + OFF_W2P);
  float* sc   = (float*)(ws + OFF_STATS);
  float* sh   = sc + 64;
  bf16*  h    = (bf16*)(ws + OFF_H);
  float* part = (float*)(ws + OFF_H);      // aliases h (h dead after k_hm)
  float* p2   = (float*)(ws + OFF_P2);
  bf16*  hm   = (bf16*)(ws + OFF_HM);
  bf16*  y2   = (bf16*)(ws + OFF_HM);      // aliases hm (dead after conv1)
  bf16*  x2t  = (bf16*)(ws + OFF_X2T);
  bf16*  y    = (bf16*)(ws + OFF_Y);
  float* out  = (float*)d_out;

  k_permw<<<336, 256, 0, stream>>>(conv1_w, conv2_w, w1p, w2p);
  k_h<<<dim3(161, 2), 256, 0, stream>>>(x1, up_fc_w, up_fc_b, h);
  k_hm<<<dim3(NTC, 2), 256, 0, stream>>>(h, up_neigh, hm);
  k_x2t<<<dim3(NTC, 2), 256, 0, stream>>>(x2, x2t);
  k_conv1<<<dim3(NTC, 2), 256, 0, stream>>>(hm, x2t, conv_nei, w1p, conv1_b, y, part);
  k_red1<<<64, 256, 0, stream>>>(part, 2 * NTC, p2);
  k_stats<<<1, 128, 0, stream>>>(p2, bn1_g, bn1_b, sc, sh);
  k_conv2<<<dim3(NTC, 2), 256, 0, stream>>>(y, conv_nei, w2p, conv2_b, sc, sh, y2, part);
  k_red1<<<64, 256, 0, stream>>>(part, 2 * NTC, p2);
  k_stats<<<1, 128, 0, stream>>>(p2, bn2_g, bn2_b, sc, sh);
  k_final<<<dim3(NTC, 2), 256, 0, stream>>>(y2, sc, sh, out);
}

// Round 9
// 331.693 us; speedup vs baseline: 1.8665x; 1.0144x over previous
//
#include <hip/hip_runtime.h>
#include <hip/hip_bf16.h>

typedef __hip_bfloat16 bf16;
typedef short bf16x8 __attribute__((ext_vector_type(8)));   // 8 bf16 = 16B (4 VGPRs)
typedef float f32x4 __attribute__((ext_vector_type(4)));

#define ND     40962
#define NUP    163842
#define NBATCH 2
#define NTC    2561            // ceil(NUP/64)
#define BN_EPS 1e-5
#define SLOPE  0.2f

// ---- ws layout (bytes) ----
#define OFF_W1P   0ull                      // 64*896*2  = 114688
#define OFF_W2P   114688ull                 // 64*448*2  = 57344
#define OFF_STATS 172032ull                 // sc[64]+sh[64] fp32
#define OFF_H     173056ull                 // h bf16: 2*40962*64*2 = 10486272 ; partials alias
#define OFF_P2    (OFF_H + 2622464ull)      // p2 (64KB) aliases h tail
#define OFF_HM    10659328ull               // hm bf16: 2*163842*64*2 = 41943552 ; y2 aliases
#define OFF_X2T   52602880ull               // x2t bf16: 41943552
#define OFF_Y     94546432ull               // y bf16: 41943552
// total ≈ 136.5 MB

__device__ __forceinline__ void gload_lds16(const void* g, void* l) {
  __builtin_amdgcn_global_load_lds(
      (const __attribute__((address_space(1))) void*)g,
      (__attribute__((address_space(3))) void*)l, 16, 0, 0);
}

__device__ __forceinline__ float lrelu(float v) { return v >= 0.0f ? v : SLOPE * v; }

// ---------------- K0: permute + bf16-convert conv weights: f' = kk*C + c ----------------
__global__ __launch_bounds__(256) void k_permw(const float* __restrict__ w1,
                                               const float* __restrict__ w2,
                                               bf16* __restrict__ w1p, bf16* __restrict__ w2p) {
  int t = blockIdx.x * 256 + threadIdx.x;
  if (t < 64 * 896) {
    int o = t / 896, f = t % 896;
    int kk = f / 128, c = f % 128;
    w1p[t] = __float2bfloat16(w1[o * 896 + c * 7 + kk]);
  } else if (t < 64 * 896 + 64 * 448) {
    int idx = t - 64 * 896;
    int o = idx / 448, f = idx % 448;
    int kk = f / 64, c = f % 64;
    w2p[idx] = __float2bfloat16(w2[o * 448 + c * 7 + kk]);
  }
}

// ---------------- K1: h[b,n,o] (bf16 node-major). 64 nodes/block, 16 outs/thread -------------
__global__ __launch_bounds__(256) void k_h(const float* __restrict__ x1,
                                           const float* __restrict__ wfc,
                                           const float* __restrict__ bfc,
                                           bf16* __restrict__ h) {
  __shared__ float wl[128 * 64];   // wl[c*64+o]
  __shared__ float bl[64];
  int tid = threadIdx.x, b = blockIdx.y;
  for (int i = tid; i < 8192; i += 256) { int o = i >> 7, c = i & 127; wl[c * 64 + o] = wfc[i]; }
  if (tid < 64) bl[tid] = bfc[tid];
  __syncthreads();
  int ln = tid & 63, wv = tid >> 6;          // node-lane, out-group (wave-uniform)
  int n = blockIdx.x * 64 + ln;
  int nc = n < ND ? n : ND - 1;
  float acc[16];
#pragma unroll
  for (int j = 0; j < 16; ++j) acc[j] = bl[wv * 16 + j];
#pragma unroll 4
  for (int c = 0; c < 128; ++c) {
    float xv = x1[((size_t)b * 128 + c) * (size_t)ND + nc];
    const f32x4* wrow = (const f32x4*)(wl + c * 64 + wv * 16);   // wave-uniform -> broadcast
#pragma unroll
    for (int g = 0; g < 4; ++g) {
      f32x4 wvv = wrow[g];
      acc[g * 4 + 0] = fmaf(xv, wvv[0], acc[g * 4 + 0]);
      acc[g * 4 + 1] = fmaf(xv, wvv[1], acc[g * 4 + 1]);
      acc[g * 4 + 2] = fmaf(xv, wvv[2], acc[g * 4 + 2]);
      acc[g * 4 + 3] = fmaf(xv, wvv[3], acc[g * 4 + 3]);
    }
  }
  if (n < ND) {
    bf16* hp = h + ((size_t)b * ND + n) * 64 + wv * 16;
#pragma unroll
    for (int og = 0; og < 2; ++og) {
      union { bf16x8 v; bf16 e[8]; } u;
#pragma unroll
      for (int j = 0; j < 8; ++j) u.e[j] = __float2bfloat16(acc[og * 8 + j]);
      ((bf16x8*)hp)[og] = u.v;
    }
  }
}

// ---------------- K2: prep — hm[b,m,:]=0.5*(h[up0]+h[up1]) AND x2t[b,m,c]=bf16(x2[b,c,m]) ----
__global__ __launch_bounds__(256) void k_prep(const float* __restrict__ x2,
                                              const bf16* __restrict__ h,
                                              const int* __restrict__ upn,
                                              bf16* __restrict__ hm,
                                              bf16* __restrict__ x2t) {
  __shared__ float tt[64][65];
  __shared__ int un[64][2];
  int tid = threadIdx.x, b = blockIdx.y;
  int m0 = blockIdx.x * 64;
#pragma unroll
  for (int i = 0; i < 16; ++i) {
    int c = i * 4 + (tid >> 6);
    int ml = tid & 63;
    int m = m0 + ml; if (m >= NUP) m = NUP - 1;
    tt[c][ml] = x2[((size_t)b * 64 + c) * (size_t)NUP + m];
  }
  if (tid < 128) {
    int ml = tid >> 1, w = tid & 1;
    int m = m0 + ml; if (m >= NUP) m = NUP - 1;
    un[ml][w] = upn[(size_t)m * 2 + w];
  }
  __syncthreads();
  int ln = tid >> 2, p = tid & 3;            // 4 threads per node, 32B seg each
  int m = m0 + ln;
  if (m >= NUP) return;
  // hm part
  {
    const bf16* h0 = h + ((size_t)b * ND + un[ln][0]) * 64 + p * 16;
    const bf16* h1 = h + ((size_t)b * ND + un[ln][1]) * 64 + p * 16;
    bf16* d = hm + ((size_t)b * NUP + m) * 64 + p * 16;
#pragma unroll
    for (int q = 0; q < 2; ++q) {
      union { bf16x8 v; bf16 e[8]; } a, bb, o_;
      a.v = ((const bf16x8*)h0)[q];
      bb.v = ((const bf16x8*)h1)[q];
#pragma unroll
      for (int j = 0; j < 8; ++j)
        o_.e[j] = __float2bfloat16(0.5f * (__bfloat162float(a.e[j]) + __bfloat162float(bb.e[j])));
      ((bf16x8*)d)[q] = o_.v;
    }
  }
  // x2t part
  {
    bf16* d = x2t + ((size_t)b * NUP + m) * 64 + p * 16;
#pragma unroll
    for (int q = 0; q < 2; ++q) {
      union { bf16x8 v; bf16 e[8]; } o_;
#pragma unroll
      for (int j = 0; j < 8; ++j) o_.e[j] = __float2bfloat16(tt[p * 16 + q * 8 + j][ln]);
      ((bf16x8*)d)[q] = o_.v;
    }
  }
}

// ---------------- K3: conv1 — 64ch (128B-row) steps, A+W DMA dbuf, 1 barrier/step ------------
// Step t: kk = t>>1, half = t&1 (0 -> hm, 1 -> x2t). Requests are 8-lane 128B (L2 line).
__global__ __launch_bounds__(256, 4) void k_conv1(const bf16* __restrict__ hm,
                                                  const bf16* __restrict__ x2t,
                                                  const int* __restrict__ neigh,
                                                  const bf16* __restrict__ wp,
                                                  const float* __restrict__ bias,
                                                  bf16* __restrict__ y,
                                                  float* __restrict__ partials) {
  constexpr int NSTEP = 14;
  __shared__ bf16 lA[2][64 * 64];            // 8KB each
  __shared__ bf16 lW[2][64 * 64];
  __shared__ int nbl[448];

  int tid = threadIdx.x, b = blockIdx.y;
  int n0 = blockIdx.x * 64;
  int wv = tid >> 6, lane = tid & 63;
  int l15 = lane & 15, l4 = lane >> 4;

  for (int j = tid; j < 448; j += 256) {
    int gi = n0 * 7 + j;
    int gmax = NUP * 7 - 1;
    nbl[j] = neigh[gi <= gmax ? gi : gmax];
  }

  f32x4 acc[4];
#pragma unroll
  for (int ot = 0; ot < 4; ++ot) {
    float bv = bias[ot * 16 + l15];
    acc[ot] = (f32x4){bv, bv, bv, bv};
  }

  const bf16* hmb  = hm  + (size_t)b * NUP * 64;
  const bf16* x2tb = x2t + (size_t)b * NUP * 64;
  // staging lane map: per array 8 DMA instrs (2/wave), instr covers 8 rows x 128B
  const int lrow = lane >> 3;                // row within instr
  const int g    = ((lane & 7) ^ lrow) * 8;  // pre-swizzled slot (elems), row&7 == lrow

  auto STAGE = [&](int buf, int t) {
    int kk = t >> 1;
    const bf16* src = (t & 1) ? x2tb : hmb;
#pragma unroll
    for (int i = 0; i < 2; ++i) {
      int srow = wv * 16 + i * 8 + lrow;
      int node = nbl[srow * 7 + kk];
      gload_lds16(src + (size_t)node * 64 + g, &lA[buf][(wv * 16 + i * 8) * 64]);
      gload_lds16(wp + (size_t)srow * 896 + t * 64 + g, &lW[buf][(wv * 16 + i * 8) * 64]);
    }
  };

  const int r = wv * 16 + l15;

  __syncthreads();                           // nbl ready
  STAGE(0, 0);
  __syncthreads();                           // step 0 staged (implicit vmcnt(0))

  int buf = 0;
#pragma unroll
  for (int t = 0; t < NSTEP; ++t) {
    if (t + 1 < NSTEP) STAGE(buf ^ 1, t + 1);
#pragma unroll
    for (int ks = 0; ks < 2; ++ks) {
      int sa = ks * 4 + l4;                  // 0..7
      bf16x8 a = *(const bf16x8*)(&lA[buf][r * 64 + ((sa ^ (r & 7)) * 8)]);
#pragma unroll
      for (int ot = 0; ot < 4; ++ot) {
        int o = ot * 16 + l15;
        bf16x8 bb = *(const bf16x8*)(&lW[buf][o * 64 + ((sa ^ (o & 7)) * 8)]);
        acc[ot] = __builtin_amdgcn_mfma_f32_16x16x32_bf16(a, bb, acc[ot], 0, 0, 0);
      }
    }
    __syncthreads();
    buf ^= 1;
  }

  float* lred = (float*)&lA[0][0];
  float s[4], q[4];
#pragma unroll
  for (int ot = 0; ot < 4; ++ot) { s[ot] = 0.0f; q[ot] = 0.0f; }
  bf16* yb = y + (size_t)b * NUP * 64;
  int nodebase = n0 + wv * 16 + l4 * 4;
#pragma unroll
  for (int i = 0; i < 4; ++i) {
    int node = nodebase + i;
    bool ok = node < NUP;
#pragma unroll
    for (int ot = 0; ot < 4; ++ot) {
      float v = acc[ot][i];
      if (ok) {
        yb[(size_t)node * 64 + ot * 16 + l15] = __float2bfloat16(v);
        s[ot] += v; q[ot] += v * v;
      }
    }
  }
#pragma unroll
  for (int ot = 0; ot < 4; ++ot) {
    s[ot] += __shfl_xor(s[ot], 16); s[ot] += __shfl_xor(s[ot], 32);
    q[ot] += __shfl_xor(q[ot], 16); q[ot] += __shfl_xor(q[ot], 32);
  }
  if (lane < 16) {
#pragma unroll
    for (int ot = 0; ot < 4; ++ot) {
      lred[(wv * 2 + 0) * 64 + ot * 16 + lane] = s[ot];
      lred[(wv * 2 + 1) * 64 + ot * 16 + lane] = q[ot];
    }
  }
  __syncthreads();
  if (tid < 128) {
    int which = tid >> 6, c = tid & 63;
    float p = lred[(0 * 2 + which) * 64 + c] + lred[(1 * 2 + which) * 64 + c] +
              lred[(2 * 2 + which) * 64 + c] + lred[(3 * 2 + which) * 64 + c];
    partials[((size_t)b * gridDim.x + blockIdx.x) * 128 + which * 64 + c] = p;
  }
}

// ---------------- K5: conv2 — full-kk steps; BN1+lrelu fused reg-staged A (padded, 1-buf) ----
// A rows are wave-private: single padded buffer [64][66] (no XOR, reads/writes <=2-way).
// Per-lane loads 2x16B at slot=lane&7 -> 8 lanes cover a row's 128B (one L2-line request).
__global__ __launch_bounds__(256, 6) void k_conv2(const bf16* __restrict__ y,
                                                  const int* __restrict__ neigh,
                                                  const bf16* __restrict__ wp,
                                                  const float* __restrict__ bias,
                                                  const float* __restrict__ sc,
                                                  const float* __restrict__ sh,
                                                  bf16* __restrict__ y2,
                                                  float* __restrict__ partials) {
  constexpr int NSTEP = 7;
  __shared__ bf16 lA[64 * 66];               // padded rows: stride 132B
  __shared__ bf16 lW[2][64 * 64];
  __shared__ int nbl[448];
  __shared__ float ssc[64], ssh[64];

  int tid = threadIdx.x, b = blockIdx.y;
  int n0 = blockIdx.x * 64;
  int wv = tid >> 6, lane = tid & 63;
  int l15 = lane & 15, l4 = lane >> 4;

  for (int j = tid; j < 448; j += 256) {
    int gi = n0 * 7 + j;
    int gmax = NUP * 7 - 1;
    nbl[j] = neigh[gi <= gmax ? gi : gmax];
  }
  if (tid < 64) { ssc[tid] = sc[tid]; ssh[tid] = sh[tid]; }

  f32x4 acc[4];
#pragma unroll
  for (int ot = 0; ot < 4; ++ot) {
    float bv = bias[ot * 16 + l15];
    acc[ot] = (f32x4){bv, bv, bv, bv};
  }

  const bf16* yb = y + (size_t)b * NUP * 64;
  const int lrow = lane >> 3;                // 0..7
  const int slot = lane & 7;
  const int gw   = (slot ^ lrow) * 8;        // W pre-swizzle (srow&7 == lrow)

  bf16x8 anext[2];
  auto STAGE_W = [&](int buf, int kk) {
#pragma unroll
    for (int i = 0; i < 2; ++i) {
      int srow = wv * 16 + i * 8 + lrow;
      gload_lds16(wp + (size_t)srow * 448 + kk * 64 + gw, &lW[buf][(wv * 16 + i * 8) * 64]);
    }
  };
  auto ALOAD = [&](int kk) {
#pragma unroll
    for (int i = 0; i < 2; ++i) {
      int srow = wv * 16 + i * 8 + lrow;
      int node = nbl[srow * 7 + kk];
      anext[i] = *(const bf16x8*)(yb + (size_t)node * 64 + slot * 8);
    }
  };
  auto BNW = [&]() {
#pragma unroll
    for (int i = 0; i < 2; ++i) {
      int srow = wv * 16 + i * 8 + lrow;
      union { bf16x8 v; bf16 e[8]; } u, o_;
      u.v = anext[i];
#pragma unroll
      for (int j = 0; j < 8; ++j) {
        int c = slot * 8 + j;
        float f = __bfloat162float(u.e[j]);
        o_.e[j] = __float2bfloat16(lrelu(fmaf(f, ssc[c], ssh[c])));
      }
      *(bf16x8*)(&lA[srow * 66 + slot * 8]) = o_.v;
    }
  };

  const int r = wv * 16 + l15;

  __syncthreads();                           // nbl, ssc ready
  STAGE_W(0, 0); ALOAD(0);
  __syncthreads();                           // W(0) staged, A(0) loads drained
  BNW();

  int buf = 0;
#pragma unroll
  for (int t = 0; t < NSTEP; ++t) {
    if (t + 1 < NSTEP) { STAGE_W(buf ^ 1, t + 1); ALOAD(t + 1); }
#pragma unroll
    for (int ks = 0; ks < 2; ++ks) {
      int sa = ks * 4 + l4;
      bf16x8 a = *(const bf16x8*)(&lA[r * 66 + sa * 8]);      // padded: no XOR needed
#pragma unroll
      for (int ot = 0; ot < 4; ++ot) {
        int o = ot * 16 + l15;
        bf16x8 bb = *(const bf16x8*)(&lW[buf][o * 64 + ((sa ^ (o & 7)) * 8)]);
        acc[ot] = __builtin_amdgcn_mfma_f32_16x16x32_bf16(a, bb, acc[ot], 0, 0, 0);
      }
    }
    __syncthreads();                         // drains W-DMA(t+1) and ALOAD(t+1)
    if (t + 1 < NSTEP) BNW();                // write own rows for t+1 (wave-private)
    buf ^= 1;
  }

  float* lred = (float*)&lA[0];
  float s[4], q[4];
#pragma unroll
  for (int ot = 0; ot < 4; ++ot) { s[ot] = 0.0f; q[ot] = 0.0f; }
  bf16* yo = y2 + (size_t)b * NUP * 64;
  int nodebase = n0 + wv * 16 + l4 * 4;
#pragma unroll
  for (int i = 0; i < 4; ++i) {
    int node = nodebase + i;
    bool ok = node < NUP;
#pragma unroll
    for (int ot = 0; ot < 4; ++ot) {
      float v = acc[ot][i];
      if (ok) {
        yo[(size_t)node * 64 + ot * 16 + l15] = __float2bfloat16(v);
        s[ot] += v; q[ot] += v * v;
      }
    }
  }
#pragma unroll
  for (int ot = 0; ot < 4; ++ot) {
    s[ot] += __shfl_xor(s[ot], 16); s[ot] += __shfl_xor(s[ot], 32);
    q[ot] += __shfl_xor(q[ot], 16); q[ot] += __shfl_xor(q[ot], 32);
  }
  __syncthreads();                           // acc reads of lA done before lred overwrite
  if (lane < 16) {
#pragma unroll
    for (int ot = 0; ot < 4; ++ot) {
      lred[(wv * 2 + 0) * 64 + ot * 16 + lane] = s[ot];
      lred[(wv * 2 + 1) * 64 + ot * 16 + lane] = q[ot];
    }
  }
  __syncthreads();
  if (tid < 128) {
    int which = tid >> 6, c = tid & 63;
    float p = lred[(0 * 2 + which) * 64 + c] + lred[(1 * 2 + which) * 64 + c] +
              lred[(2 * 2 + which) * 64 + c] + lred[(3 * 2 + which) * 64 + c];
    partials[((size_t)b * gridDim.x + blockIdx.x) * 128 + which * 64 + c] = p;
  }
}

// ---------------- K4a: tree-reduce partials (nblk x 128) -> (128 x 128) ----------------------
__global__ __launch_bounds__(256) void k_red1(const float* __restrict__ p, int nblk,
                                              float* __restrict__ p2) {
  int g = blockIdx.x * 2 + threadIdx.x / 128;
  int j = threadIdx.x & 127;
  float a = 0.0f;
  for (int r = g; r < nblk; r += 128) a += p[(size_t)r * 128 + j];
  p2[(size_t)g * 128 + j] = a;
}

// ---------------- K4b: finalize BN: sc = g*rsqrt(var+eps), sh = beta - mean*sc ---------------
__global__ __launch_bounds__(128) void k_stats(const float* __restrict__ p2,
                                               const float* __restrict__ g,
                                               const float* __restrict__ be,
                                               float* __restrict__ sc, float* __restrict__ sh) {
  __shared__ double red[128];
  int j = threadIdx.x;
  double a = 0.0;
  for (int r = 0; r < 128; ++r) a += (double)p2[r * 128 + j];
  red[j] = a;
  __syncthreads();
  if (j < 64) {
    double M = (double)NBATCH * (double)NUP;
    double mean = red[j] / M;
    double var = red[64 + j] / M - mean * mean;
    float s = g[j] * (float)(1.0 / sqrt(var + BN_EPS));
    sc[j] = s;
    sh[j] = be[j] - (float)mean * s;
  }
}

// ---------------- K8: out[b,c,n] = lrelu(y2[b,n,c]*sc+sh)  (transpose to channel-major) ------
__global__ __launch_bounds__(256) void k_final(const bf16* __restrict__ y,
                                               const float* __restrict__ sc,
                                               const float* __restrict__ sh,
                                               float* __restrict__ out) {
  __shared__ float t[64][65];
  __shared__ float ssc[64], ssh[64];
  int tid = threadIdx.x, b = blockIdx.y;
  int n0 = blockIdx.x * 64;
  if (tid < 64) { ssc[tid] = sc[tid]; ssh[tid] = sh[tid]; }
  __syncthreads();
  int ln = tid >> 2, qc = tid & 3;
  int n = n0 + ln; if (n >= NUP) n = NUP - 1;
  const bf16* yp = y + ((size_t)b * NUP + n) * 64 + qc * 16;
  union { bf16x8 v; bf16 el[8]; } v0, v1;
  v0.v = ((const bf16x8*)yp)[0];
  v1.v = ((const bf16x8*)yp)[1];
#pragma unroll
  for (int j = 0; j < 8; ++j) {
    int c = qc * 16 + j;
    t[ln][c] = lrelu(fmaf(__bfloat162float(v0.el[j]), ssc[c], ssh[c]));
  }
#pragma unroll
  for (int j = 0; j < 8; ++j) {
    int c = qc * 16 + 8 + j;
    t[ln][c] = lrelu(fmaf(__bfloat162float(v1.el[j]), ssc[c], ssh[c]));
  }
  __syncthreads();
  int nl = tid & 63;
  int nn = n0 + nl;
  if (nn >= NUP) return;
#pragma unroll
  for (int i = 0; i < 16; ++i) {
    int c = i * 4 + (tid >> 6);
    out[((size_t)b * 64 + c) * (size_t)NUP + nn] = t[nl][c];
  }
}

extern "C" void kernel_launch(void* const* d_in, const int* in_sizes, int n_in,
                              void* d_out, int out_size, void* d_ws, size_t ws_size,
                              hipStream_t stream) {
  const float* x1      = (const float*)d_in[0];
  const float* x2      = (const float*)d_in[1];
  const float* up_fc_w = (const float*)d_in[2];
  const float* up_fc_b = (const float*)d_in[3];
  const float* conv1_w = (const float*)d_in[4];
  const float* conv1_b = (const float*)d_in[5];
  const float* bn1_g   = (const float*)d_in[6];
  const float* bn1_b   = (const float*)d_in[7];
  const float* conv2_w = (const float*)d_in[8];
  const float* conv2_b = (const float*)d_in[9];
  const float* bn2_g   = (const float*)d_in[10];
  const float* bn2_b   = (const float*)d_in[11];
  const int* up_neigh  = (const int*)d_in[12];
  const int* conv_nei  = (const int*)d_in[13];

  char* ws = (char*)d_ws;
  bf16*  w1p  = (bf16*)(ws + OFF_W1P);
  bf16*  w2p  = (bf16*)(ws + OFF_W2P);
  float* sc   = (float*)(ws + OFF_STATS);
  float* sh   = sc + 64;
  bf16*  h    = (bf16*)(ws + OFF_H);
  float* part = (float*)(ws + OFF_H);      // aliases h (h dead after k_prep)
  float* p2   = (float*)(ws + OFF_P2);
  bf16*  hm   = (bf16*)(ws + OFF_HM);
  bf16*  y2   = (bf16*)(ws + OFF_HM);      // aliases hm (dead after conv1)
  bf16*  x2t  = (bf16*)(ws + OFF_X2T);
  bf16*  y    = (bf16*)(ws + OFF_Y);
  float* out  = (float*)d_out;

  k_permw<<<336, 256, 0, stream>>>(conv1_w, conv2_w, w1p, w2p);
  k_h<<<dim3(641, 2), 256, 0, stream>>>(x1, up_fc_w, up_fc_b, h);
  k_prep<<<dim3(NTC, 2), 256, 0, stream>>>(x2, h, up_neigh, hm, x2t);
  k_conv1<<<dim3(NTC, 2), 256, 0, stream>>>(hm, x2t, conv_nei, w1p, conv1_b, y, part);
  k_red1<<<64, 256, 0, stream>>>(part, 2 * NTC, p2);
  k_stats<<<1, 128, 0, stream>>>(p2, bn1_g, bn1_b, sc, sh);
  k_conv2<<<dim3(NTC, 2), 256, 0, stream>>>(y, conv_nei, w2p, conv2_b, sc, sh, y2, part);
  k_red1<<<64, 256, 0, stream>>>(part, 2 * NTC, p2);
  k_stats<<<1, 128, 0, stream>>>(p2, bn2_g, bn2_b, sc, sh);
  k_final<<<dim3(NTC, 2), 256, 0, stream>>>(y2, sc, sh, out);
}